// Round 6
// baseline (338.071 us; speedup 1.0000x reference)
//
#include <hip/hip_runtime.h>

#define G 8
#define S 2048
#define DMODEL 1024
#define NE 8
#define TOKENS (G * S)
#define GATE_BLOCKS 512
#define FILL_BLOCKS 8192

// ---------------------------------------------------------------------------
// K1: fused gate + dense zero-fill.
// Blocks [0, GATE_BLOCKS): gating logits + softmax + top-2. 4 waves/block,
//   each wave owns 8 consecutive tokens; W (1024x8 = 32KB) preloaded into
//   128 VGPRs per wave; x loads are float4 (16B/lane, G13).
// Blocks [GATE_BLOCKS, GATE_BLOCKS+FILL_BLOCKS): float4 zero-fill of the
//   whole output (combine + dispatch contiguous). Independent of gate, so
//   its 267 MB write stream overlaps gate's 64 MB read stream.
// ---------------------------------------------------------------------------
__global__ __launch_bounds__(256) void gate_zerofill_kernel(
    const float* __restrict__ x, const float* __restrict__ W,
    const float* __restrict__ bias, int* __restrict__ idx01,
    float* __restrict__ g0out, float* __restrict__ g1out,
    float4* __restrict__ out4, int nchunks_total) {
  if (blockIdx.x >= GATE_BLOCKS) {
    // ---- zero-fill path ----
    const int fidx = blockIdx.x - GATE_BLOCKS;
    const float4 z = make_float4(0.f, 0.f, 0.f, 0.f);
    const int stride = FILL_BLOCKS * 256;
    for (int i = fidx * 256 + threadIdx.x; i < nchunks_total; i += stride)
      out4[i] = z;
    return;
  }

  // ---- gate path ----
  const int lane = threadIdx.x & 63;
  const int wave = threadIdx.x >> 6;
  const int tok0 = blockIdx.x * 32 + wave * 8;

  // W4[d*2] = experts 0-3 of row d; W4[d*2+1] = experts 4-7.
  const float4* W4 = (const float4*)W;
  float4 wa[4][4], wb[4][4];
#pragma unroll
  for (int c = 0; c < 4; ++c) {
#pragma unroll
    for (int j = 0; j < 4; ++j) {
      int d = 4 * (lane + (c << 6)) + j;
      wa[c][j] = W4[d * 2];
      wb[c][j] = W4[d * 2 + 1];
    }
  }
  float b[8];
#pragma unroll
  for (int e = 0; e < 8; ++e) b[e] = bias[e];

  for (int t = 0; t < 8; ++t) {
    const int tok = tok0 + t;
    const float4* xp = (const float4*)(x + (size_t)tok * DMODEL);
    float acc[8] = {0.f, 0.f, 0.f, 0.f, 0.f, 0.f, 0.f, 0.f};
#pragma unroll
    for (int c = 0; c < 4; ++c) {
      float4 xv = xp[lane + (c << 6)];
      const float xs[4] = {xv.x, xv.y, xv.z, xv.w};  // static-indexed
#pragma unroll
      for (int j = 0; j < 4; ++j) {
        float s = xs[j];
        acc[0] = fmaf(s, wa[c][j].x, acc[0]);
        acc[1] = fmaf(s, wa[c][j].y, acc[1]);
        acc[2] = fmaf(s, wa[c][j].z, acc[2]);
        acc[3] = fmaf(s, wa[c][j].w, acc[3]);
        acc[4] = fmaf(s, wb[c][j].x, acc[4]);
        acc[5] = fmaf(s, wb[c][j].y, acc[5]);
        acc[6] = fmaf(s, wb[c][j].z, acc[6]);
        acc[7] = fmaf(s, wb[c][j].w, acc[7]);
      }
    }
    // 64-lane butterfly reduce, 8 independent chains
#pragma unroll
    for (int e = 0; e < 8; ++e) {
      float v = acc[e];
#pragma unroll
      for (int off = 1; off < 64; off <<= 1) v += __shfl_xor(v, off);
      acc[e] = v + b[e];
    }
    if (lane == 0) {
      float m = acc[0];
#pragma unroll
      for (int e = 1; e < 8; ++e) m = fmaxf(m, acc[e]);
      float p[8], sum = 0.f;
#pragma unroll
      for (int e = 0; e < 8; ++e) {
        p[e] = __expf(acc[e] - m);
        sum += p[e];
      }
      // top-2 by logit (softmax monotone); first-index wins ties
      int i0 = 0;
      float best = acc[0];
#pragma unroll
      for (int e = 1; e < 8; ++e)
        if (acc[e] > best) { best = acc[e]; i0 = e; }
      int i1 = -1;
      float b1 = 0.f;
#pragma unroll
      for (int e = 0; e < 8; ++e) {
        if (e == i0) continue;
        if (i1 < 0 || acc[e] > b1) { b1 = acc[e]; i1 = e; }
      }
      float inv = 1.0f / sum;
      idx01[tok] = i0 | (i1 << 8);
      g0out[tok] = p[i0] * inv;
      g1out[tok] = p[i1] * inv;
    }
  }
}

// ---------------------------------------------------------------------------
// K2: k-separate cumsum scan + direct scatter of nonzeros.
// Reference semantics: cumsum over axis=1 (S) with the k-dim SEPARATE —
// top-1 and top-2 assignments to the same expert use INDEPENDENT counters.
// 4 packed uint64 words: a0/a1 = k=0 experts 0-3/4-7; b0/b1 = k=1.
// Output was pre-zeroed by K1 (same stream => ordered); here we write only
// the <=2 nonzero slots per token: combine[row*slots+pos-1]=gate, dispatch=1.
// ---------------------------------------------------------------------------
__global__ __launch_bounds__(256) void scan_scatter_kernel(
    const int* __restrict__ idx01, const float* __restrict__ g0,
    const float* __restrict__ g1, float* __restrict__ combine,
    float* __restrict__ dispatch, int slots) {
  const int g = blockIdx.x;
  const int t = threadIdx.x;
  const int lane = t & 63;
  const int wave = t >> 6;
  const int base = g * S + t * 8;

  int loc[8];
  unsigned long long a0 = 0ULL, a1 = 0ULL, b0 = 0ULL, b1 = 0ULL;
#pragma unroll
  for (int i = 0; i < 8; ++i) {
    int v = idx01[base + i];
    loc[i] = v;
    int i0 = v & 0xFF, i1 = (v >> 8) & 0xFF;
    if (i0 < 4) a0 += 1ULL << (16 * i0); else a1 += 1ULL << (16 * (i0 & 3));
    if (i1 < 4) b0 += 1ULL << (16 * i1); else b1 += 1ULL << (16 * (i1 & 3));
  }
  const unsigned long long la0 = a0, la1 = a1, lb0 = b0, lb1 = b1;

#pragma unroll
  for (int off = 1; off < 64; off <<= 1) {
    unsigned long long u0 = __shfl_up(a0, (unsigned)off);
    unsigned long long u1 = __shfl_up(a1, (unsigned)off);
    unsigned long long u2 = __shfl_up(b0, (unsigned)off);
    unsigned long long u3 = __shfl_up(b1, (unsigned)off);
    if (lane >= off) { a0 += u0; a1 += u1; b0 += u2; b1 += u3; }
  }

  __shared__ unsigned long long wt[4][4];
  if (lane == 63) {
    wt[wave][0] = a0; wt[wave][1] = a1; wt[wave][2] = b0; wt[wave][3] = b1;
  }
  __syncthreads();
  for (int w = 0; w < wave; ++w) {
    a0 += wt[w][0]; a1 += wt[w][1]; b0 += wt[w][2]; b1 += wt[w][3];
  }

  a0 -= la0; a1 -= la1; b0 -= lb0; b1 -= lb1;  // exclusive prefix

#pragma unroll
  for (int i = 0; i < 8; ++i) {
    const int tok = base + i;
    int v = loc[i];
    int i0 = v & 0xFF, i1 = (v >> 8) & 0xFF;
    int p0, p1;
    {
      int sh = 16 * (i0 & 3);
      if (i0 < 4) { p0 = (int)((a0 >> sh) & 0xFFFF) + 1; a0 += 1ULL << sh; }
      else        { p0 = (int)((a1 >> sh) & 0xFFFF) + 1; a1 += 1ULL << sh; }
    }
    {
      int sh = 16 * (i1 & 3);
      if (i1 < 4) { p1 = (int)((b0 >> sh) & 0xFFFF) + 1; b0 += 1ULL << sh; }
      else        { p1 = (int)((b1 >> sh) & 0xFFFF) + 1; b1 += 1ULL << sh; }
    }
    if (p0 <= slots) {
      size_t off0 = (size_t)(tok * NE + i0) * (size_t)slots + (size_t)(p0 - 1);
      combine[off0] = g0[tok];
      dispatch[off0] = 1.f;
    }
    if (p1 <= slots) {
      size_t off1 = (size_t)(tok * NE + i1) * (size_t)slots + (size_t)(p1 - 1);
      combine[off1] = g1[tok];
      dispatch[off1] = 1.f;
    }
  }
}

// ---------------------------------------------------------------------------
extern "C" void kernel_launch(void* const* d_in, const int* in_sizes, int n_in,
                              void* d_out, int out_size, void* d_ws,
                              size_t ws_size, hipStream_t stream) {
  const float* x = (const float*)d_in[0];
  const float* W = (const float*)d_in[1];
  const float* bias = (const float*)d_in[2];

  float* out = (float*)d_out;
  const int rows = TOKENS * NE;             // 131072
  const int slots = out_size / (2 * rows);  // 255 (= capacity - 1)
  float* combine = out;
  float* dispatch = out + (size_t)(out_size / 2);

  char* ws = (char*)d_ws;
  int* idx01 = (int*)(ws + 0);
  float* g0 = (float*)(ws + TOKENS * 4);
  float* g1 = (float*)(ws + TOKENS * 8);

  const int nchunks_total = out_size >> 2;  // out_size divisible by 4

  gate_zerofill_kernel<<<GATE_BLOCKS + FILL_BLOCKS, 256, 0, stream>>>(
      x, W, bias, idx01, g0, g1, (float4*)out, nchunks_total);
  scan_scatter_kernel<<<G, 256, 0, stream>>>(idx01, g0, g1, combine, dispatch,
                                             slots);
}